// Round 19
// baseline (79.165 us; speedup 1.0000x reference)
//
#include <hip/hip_runtime.h>
#include <cstdint>

static constexpr int B    = 16;
static constexpr int P    = 22536;
static constexpr int NOBJ = 32;
static constexpr int NCLS = 80;
static constexpr int CHUNKS = (P + 255) / 256;   // 89
static constexpr int NBLK   = CHUNKS * B;        // 1424 bulk / prep blocks
static constexpr int OBJB   = B * NOBJ;          // 512 objbest blocks

// neg-path focal term (before the 0.75 weight): p^2*(x+log u), u=1+e^-x, p=1/u
__device__ __forceinline__ float negterm(float x) {
  float e  = __expf(-x);
  float u  = 1.f + e;
  float r  = __builtin_amdgcn_rcpf(u);
  float lu = __logf(u);
  return (x + lu) * (r * r);
}

// ---------------------------------------------------------------- Node 1: pure bulk focal + objbest (division-free scan)
// Byte-identical to R15 (best: 51.6 us) except block 0 zeroes the prep
// done-counter (visible across the kernel boundary).
__global__ __launch_bounds__(256, 4) void k_bulk(
    const float4* __restrict__ scores, const float4* __restrict__ boxes,
    const float4* __restrict__ priors,
    float* __restrict__ partB, unsigned long long* __restrict__ objbest,
    unsigned* __restrict__ counter) {
  const int bid = blockIdx.x;
  const int tid = threadIdx.x;
  if (bid == 0 && tid == 0) *counter = 0u;
  if (bid < NBLK) {
    const int b    = bid / CHUNKS;
    const int base = (bid - b * CHUNKS) * 256;
    const int nval = (P - base < 256) ? (P - base) : 256;
    const float4* srow = scores + ((size_t)b * P + base) * 20;
    float acc = 0.f;
    if (nval == 256) {                   // full chunk: 5120 float4, unguarded
      #pragma unroll
      for (int bt = 0; bt < 2; ++bt) {
        float4 s[10];
        const int i0 = tid + bt * 2560;
        #pragma unroll
        for (int j = 0; j < 10; ++j) s[j] = srow[i0 + j * 256];  // coalesced
        #pragma unroll
        for (int j = 0; j < 10; ++j)
          acc += negterm(s[j].x) + negterm(s[j].y)
               + negterm(s[j].z) + negterm(s[j].w);
      }
    } else {                             // tail chunk (1 per image)
      const int lim = nval * 20;
      for (int idx = tid; idx < lim; idx += 256) {
        float4 s = srow[idx];
        acc += negterm(s.x) + negterm(s.y) + negterm(s.z) + negterm(s.w);
      }
    }
    acc *= 0.75f;
    for (int off = 32; off > 0; off >>= 1) acc += __shfl_down(acc, off, 64);
    __shared__ float sv[4];
    int lane = tid & 63, wid = tid >> 6;
    if (lane == 0) sv[wid] = acc;
    __syncthreads();
    if (tid == 0) partB[bid] = sv[0] + sv[1] + sv[2] + sv[3];
  } else {
    // -------- objbest role: division-free argmax scan
    const int bid2 = bid - NBLK;
    const int b = bid2 >> 5;
    const int o = bid2 & (NOBJ - 1);
    float4 bx = boxes[b * NOBJ + o];
    float barea = (bx.z - bx.x) * (bx.w - bx.y);   // reference op order
    float bi = 0.f, bu = 1.f; int bp = P;          // best inter/union/prior
    #pragma unroll 4
    for (int p = tid; p < P; p += 256) {
      float4 pc = priors[p];
      float hx = pc.z * 0.5f, hy = pc.w * 0.5f;    // c/2. == c*0.5f exactly
      float px0 = pc.x - hx, py0 = pc.y - hy;
      float px1 = pc.x + hx, py1 = pc.y + hy;
      float parea = (px1 - px0) * (py1 - py0);
      float lx = fmaxf(bx.x, px0), ly = fmaxf(bx.y, py0);
      float rx = fminf(bx.z, px1), ry = fminf(bx.w, py1);
      float w = fmaxf(rx - lx, 0.f), h = fmaxf(ry - ly, 0.f);
      float inter = w * h;
      float uni = barea + parea - inter;           // reference operand order
      // iou_p > iou_best  <=>  inter*bu > bi*uni  (all positive)
      if (inter * bu > bi * uni) { bi = inter; bu = uni; bp = p; }
    }
    for (int off = 32; off > 0; off >>= 1) {
      float oi = __shfl_down(bi, off, 64);
      float ou = __shfl_down(bu, off, 64);
      int   op = __shfl_down(bp, off, 64);
      float l = oi * bu, r2 = bi * ou;
      if (l > r2 || (l == r2 && op < bp)) { bi = oi; bu = ou; bp = op; }
    }
    __shared__ float sbi[4], sbu[4];
    __shared__ int   sbp[4];
    int lane = tid & 63, wid = tid >> 6;
    if (lane == 0) { sbi[wid] = bi; sbu[wid] = bu; sbp[wid] = bp; }
    __syncthreads();
    if (tid == 0) {
      for (int w2 = 1; w2 < 4; ++w2) {
        float l = sbi[w2] * bu, r2 = bi * sbu[w2];
        if (l > r2 || (l == r2 && sbp[w2] < bp)) {
          bi = sbi[w2]; bu = sbu[w2]; bp = sbp[w2];
        }
      }
      float iou = bi / bu;                 // ONE IEEE div: reference bits
      objbest[bid2] =
          ((unsigned long long)__float_as_uint(iou) << 32) |
          (unsigned long long)(unsigned)(~(unsigned)bp);
    }
  }
}

// ---------------------------------------------------------------- Node 2: match + force + classloc + corrections + FINALIZE
// Matching/correction logic byte-identical to R15. Added: last-finished-block
// finalize (R5-proven: threadfence release + counter + AGENT atomic loads),
// absorbing k_final and its dispatch overhead.
__global__ __launch_bounds__(256) void k_prep(
    const float4* __restrict__ plocs, const float* __restrict__ scoresF,
    const float4* __restrict__ boxes, const int* __restrict__ labels,
    const float4* __restrict__ priors,
    const unsigned long long* __restrict__ objbest,
    const float* __restrict__ partB,
    float* __restrict__ partS, int* __restrict__ partN,
    float* __restrict__ partC, unsigned* __restrict__ counter,
    float* __restrict__ out) {
  const int b    = blockIdx.y;
  const int base = blockIdx.x * 256;
  const int tid  = threadIdx.x;
  const int p    = base + tid;
  const int lane = tid & 63, wid = tid >> 6;

  __shared__ float4 sbox[NOBJ];
  __shared__ float  sarea[NOBJ];
  __shared__ int    slab[NOBJ];
  __shared__ int    sfp[NOBJ];   // forced prior index (-1 if invalid)
  __shared__ int    sfc[NOBJ];   // filtered object index (cumsum(valid)-1)
  __shared__ int    igp[256];    // compacted ignored prior indices
  __shared__ int    wcnt[4];     // per-wave ignored counts
  __shared__ unsigned sdone;

  if (tid < NOBJ) {
    float4 bx = boxes[b * NOBJ + tid];
    sbox[tid]  = bx;
    sarea[tid] = (bx.z - bx.x) * (bx.w - bx.y);
    slab[tid]  = labels[b * NOBJ + tid];
    unsigned long long pk = objbest[b * NOBJ + tid];
    float iou  = __uint_as_float((unsigned)(pk >> 32));
    bool valid = iou > 0.f;
    unsigned long long m = __ballot(valid);       // lanes 32..63 inactive -> 0
    sfp[tid] = valid ? (int)(~(unsigned)(pk & 0xFFFFFFFFull)) : -1;
    sfc[tid] = (int)__popcll(m & ((1ull << tid) - 1ull));
  }
  __syncthreads();

  float mySl1 = 0.f, myCorr = 0.f; int myPos = 0;
  bool isig = false;
  if (p < P) {
    float4 pc = priors[p];
    float hx = pc.z * 0.5f, hy = pc.w * 0.5f;
    float px0 = pc.x - hx, py0 = pc.y - hy;
    float px1 = pc.x + hx, py1 = pc.y + hy;
    float parea = (px1 - px0) * (py1 - py0);
    float bi = 0.f, bu = 1.f; int obj = 0;       // best inter/union/object
    #pragma unroll 8
    for (int o = 0; o < NOBJ; ++o) {
      float4 bx = sbox[o];
      float lx = fmaxf(bx.x, px0), ly = fmaxf(bx.y, py0);
      float rx = fminf(bx.z, px1), ry = fminf(bx.w, py1);
      float w = fmaxf(rx - lx, 0.f), h = fmaxf(ry - ly, 0.f);
      float inter = w * h;
      float uni = sarea[o] + parea - inter;      // reference operand order
      if (inter * bu > bi * uni) { bi = inter; bu = uni; obj = o; }
      // strict >: first max wins (ascending o)
    }
    float ov = bi / bu;                          // ONE IEEE div: ref bits
    #pragma unroll
    for (int j = 0; j < NOBJ; ++j) {             // ascending j: last writer wins
      if (sfp[j] == p) { ov = 1.0f; obj = sfc[j]; }
    }
    int lab;
    if (ov < 0.4f)      lab = 0;                 // fp32(0.5-0.1) == 0.4f
    else if (ov < 0.5f) lab = -1;
    else                lab = slab[obj];
    if (lab < 0) {
      isig = true;                               // handled cooperatively below
    } else if (lab > 0) {
      myPos = 1;
      float4 bx = sbox[obj];                     // quirky filtered index, like ref
      float cx = (bx.x + bx.z) * 0.5f;
      float cy = (bx.y + bx.w) * 0.5f;
      float cw = bx.z - bx.x;
      float ch = bx.w - bx.y;
      float gx = (cx - pc.x) / (pc.z / 10.f);    // keep the /10. division
      float gy = (cy - pc.y) / (pc.w / 10.f);
      float gw = logf(cw / pc.z) * 5.f;
      float gh = logf(ch / pc.w) * 5.f;
      float4 pl = plocs[(size_t)b * P + p];
      float d, a;
      d = pl.x - gx; a = fabsf(d); mySl1 += (a < 1.f) ? 0.5f * d * d : a - 0.5f;
      d = pl.y - gy; a = fabsf(d); mySl1 += (a < 1.f) ? 0.5f * d * d : a - 0.5f;
      d = pl.z - gw; a = fabsf(d); mySl1 += (a < 1.f) ? 0.5f * d * d : a - 0.5f;
      d = pl.w - gh; a = fabsf(d); mySl1 += (a < 1.f) ? 0.5f * d * d : a - 0.5f;
      // swap the positive class's neg term for the pos term
      float x  = scoresF[((size_t)b * P + p) * NCLS + (lab - 1)];
      float e  = __expf(-x);
      float u  = 1.f + e;
      float r  = __builtin_amdgcn_rcpf(u);
      float lu = __logf(u);
      float omp = e * r;                         // 1-p
      myCorr += 0.25f * omp * omp * lu - 0.75f * (x + lu) * (r * r);
    }
  }

  // ---- deterministic compaction of ignored priors (ballot prefix, no atomics)
  unsigned long long igm = __ballot(isig);
  int wpre = (int)__popcll(igm & ((1ull << lane) - 1ull));
  if (lane == 0) wcnt[wid] = (int)__popcll(igm);
  __syncthreads();
  int wbase = 0;
  #pragma unroll
  for (int ww = 0; ww < 4; ++ww) if (ww < wid) wbase += wcnt[ww];
  const int n_ig = wcnt[0] + wcnt[1] + wcnt[2] + wcnt[3];
  if (isig) igp[wbase + wpre] = p;
  __syncthreads();

  // ---- cooperative recompute of ignored rows: 4 threads/row, 5 float4 each
  const float4* scores4 = (const float4*)scoresF;
  for (int i0 = 0; i0 < n_ig; i0 += 64) {
    int r = i0 + (tid >> 2);
    int q = tid & 3;
    float rs = 0.f;
    if (r < n_ig) {
      const float4* row = scores4 + ((size_t)b * P + igp[r]) * 20 + q * 5;
      #pragma unroll
      for (int j = 0; j < 5; ++j) {
        float4 s = row[j];                 // 80B contiguous per lane
        rs += negterm(s.x) + negterm(s.y) + negterm(s.z) + negterm(s.w);
      }
    }
    rs += __shfl_xor(rs, 1, 64);
    rs += __shfl_xor(rs, 2, 64);
    if (r < n_ig && q == 0) myCorr -= 0.75f * rs;
  }

  for (int off = 32; off > 0; off >>= 1) {
    mySl1  += __shfl_down(mySl1,  off, 64);
    myCorr += __shfl_down(myCorr, off, 64);
    myPos  += __shfl_down(myPos,  off, 64);
  }
  __shared__ float sv[4], sc2[4];
  __shared__ int   sc[4];
  if (lane == 0) { sv[wid] = mySl1; sc2[wid] = myCorr; sc[wid] = myPos; }
  __syncthreads();
  const int bid = b * CHUNKS + blockIdx.x;
  if (tid == 0) {
    partS[bid] = sv[0] + sv[1] + sv[2] + sv[3];
    partC[bid] = sc2[0] + sc2[1] + sc2[2] + sc2[3];
    partN[bid] = sc[0] + sc[1] + sc[2] + sc[3];
    __threadfence();                     // release partials device-wide
    sdone = atomicAdd(counter, 1u);
  }
  __syncthreads();
  if (sdone == NBLK - 1) {               // last-finished block finalizes
    __threadfence();                     // acquire
    float sF = 0.f, sS = 0.f; int sN = 0;
    for (int i = tid; i < NBLK; i += 256) {
      sF += partB[i];                    // node-1 writes: kernel boundary
      sF += __hip_atomic_load(&partC[i], __ATOMIC_RELAXED, __HIP_MEMORY_SCOPE_AGENT);
      sS += __hip_atomic_load(&partS[i], __ATOMIC_RELAXED, __HIP_MEMORY_SCOPE_AGENT);
      sN += __hip_atomic_load(&partN[i], __ATOMIC_RELAXED, __HIP_MEMORY_SCOPE_AGENT);
    }
    for (int off = 32; off > 0; off >>= 1) {
      sF += __shfl_down(sF, off, 64);
      sS += __shfl_down(sS, off, 64);
      sN += __shfl_down(sN, off, 64);
    }
    __shared__ float vF[4], vS[4];
    __shared__ int   vN[4];
    if (lane == 0) { vF[wid] = sF; vS[wid] = sS; vN[wid] = sN; }
    __syncthreads();
    if (tid == 0) {
      float f = vF[0] + vF[1] + vF[2] + vF[3];
      float s = vS[0] + vS[1] + vS[2] + vS[3];
      int   n = vN[0] + vN[1] + vN[2] + vN[3];
      float np = (float)(n >= 1 ? n : 1);
      out[0] = f / np + s / (np * 4.f);
    }
  }
}

// ---------------------------------------------------------------- launch
extern "C" void kernel_launch(void* const* d_in, const int* in_sizes, int n_in,
                              void* d_out, int out_size, void* d_ws, size_t ws_size,
                              hipStream_t stream) {
  const float* plocs   = (const float*)d_in[0];   // [B,P,4]
  const float* pscores = (const float*)d_in[1];   // [B,P,80]
  const float* boxes   = (const float*)d_in[2];   // [B,32,4]
  const int*   labels  = (const int*)d_in[3];     // [B,32]
  const float* priors  = (const float*)d_in[4];   // [P,4]
  float* out = (float*)d_out;

  char* w = (char*)d_ws;
  unsigned long long* objbest = (unsigned long long*)w;  // 512 u64  @0
  unsigned* counter = (unsigned*)(w + 4096);
  float* partB = (float*)(w + 8192);                     // NBLK floats
  float* partS = (float*)(w + 20480);                    // NBLK floats
  int*   partN = (int*)(w + 32768);                      // NBLK ints
  float* partC = (float*)(w + 45056);                    // NBLK floats

  k_bulk<<<NBLK + OBJB, 256, 0, stream>>>(
      (const float4*)pscores, (const float4*)boxes, (const float4*)priors,
      partB, objbest, counter);
  dim3 g(CHUNKS, B);
  k_prep<<<g, 256, 0, stream>>>(
      (const float4*)plocs, pscores, (const float4*)boxes, labels,
      (const float4*)priors, objbest, partB, partS, partN, partC,
      counter, out);
}

// Round 20
// 55.837 us; speedup vs baseline: 1.4178x; 1.4178x over previous
//
#include <hip/hip_runtime.h>
#include <cstdint>

static constexpr int B    = 16;
static constexpr int P    = 22536;
static constexpr int NOBJ = 32;
static constexpr int NCLS = 80;
static constexpr int CHUNKS = (P + 255) / 256;   // 89
static constexpr int NBLK   = CHUNKS * B;        // 1424 fused blocks
static constexpr int OBJB   = B * NOBJ;          // 512 objbest blocks

// neg-path focal term (before the 0.75 weight): p^2*(x+log u), u=1+e^-x, p=1/u
__device__ __forceinline__ float negterm(float x) {
  float e  = __expf(-x);
  float u  = 1.f + e;
  float r  = __builtin_amdgcn_rcpf(u);
  float lu = __logf(u);
  return (x + lu) * (r * r);
}

// ---------------------------------------------------------------- K1: objbest only (division-free scan)
// Per-object argmax over priors via cross-mult compares; ONE IEEE div at the
// end reproduces reference iou bits. Small (512 blocks) -> finishes fast,
// unblocking K2's match phase.
__global__ __launch_bounds__(256) void k_objbest(
    const float4* __restrict__ boxes, const float4* __restrict__ priors,
    unsigned long long* __restrict__ objbest) {
  const int bid = blockIdx.x;
  const int tid = threadIdx.x;
  const int b = bid >> 5;
  const int o = bid & (NOBJ - 1);
  float4 bx = boxes[b * NOBJ + o];
  float barea = (bx.z - bx.x) * (bx.w - bx.y);   // reference op order
  float bi = 0.f, bu = 1.f; int bp = P;          // best inter/union/prior
  #pragma unroll 4
  for (int p = tid; p < P; p += 256) {
    float4 pc = priors[p];
    float hx = pc.z * 0.5f, hy = pc.w * 0.5f;    // c/2. == c*0.5f exactly
    float px0 = pc.x - hx, py0 = pc.y - hy;
    float px1 = pc.x + hx, py1 = pc.y + hy;
    float parea = (px1 - px0) * (py1 - py0);
    float lx = fmaxf(bx.x, px0), ly = fmaxf(bx.y, py0);
    float rx = fminf(bx.z, px1), ry = fminf(bx.w, py1);
    float w = fmaxf(rx - lx, 0.f), h = fmaxf(ry - ly, 0.f);
    float inter = w * h;
    float uni = barea + parea - inter;           // reference operand order
    // iou_p > iou_best  <=>  inter*bu > bi*uni  (all positive)
    if (inter * bu > bi * uni) { bi = inter; bu = uni; bp = p; }
  }
  for (int off = 32; off > 0; off >>= 1) {
    float oi = __shfl_down(bi, off, 64);
    float ou = __shfl_down(bu, off, 64);
    int   op = __shfl_down(bp, off, 64);
    float l = oi * bu, r2 = bi * ou;
    if (l > r2 || (l == r2 && op < bp)) { bi = oi; bu = ou; bp = op; }
  }
  __shared__ float sbi[4], sbu[4];
  __shared__ int   sbp[4];
  int lane = tid & 63, wid = tid >> 6;
  if (lane == 0) { sbi[wid] = bi; sbu[wid] = bu; sbp[wid] = bp; }
  __syncthreads();
  if (tid == 0) {
    for (int w2 = 1; w2 < 4; ++w2) {
      float l = sbi[w2] * bu, r2 = bi * sbu[w2];
      if (l > r2 || (l == r2 && sbp[w2] < bp)) {
        bi = sbi[w2]; bu = sbu[w2]; bp = sbp[w2];
      }
    }
    float iou = bi / bu;                 // ONE IEEE div: reference bits
    objbest[bid] =
        ((unsigned long long)__float_as_uint(iou) << 32) |
        (unsigned long long)(unsigned)(~(unsigned)bp);
  }
}

// ---------------------------------------------------------------- K2: fused bulk focal + match + corrections
// Grid (CHUNKS, B). Phase 1: R15's bulk focal (2x10 batched coalesced float4,
// no LDS in hot loop). Phase 2: R15's prep body verbatim (div-free argmax,
// ONE IEEE div for threshold bits, forced-list ballot quirk, pos-swap,
// cooperative ignored-row recompute). Phases are register-disjoint;
// launch_bounds(256,4) keeps the 128-VGPR budget for load batching.
__global__ __launch_bounds__(256, 4) void k_fused(
    const float4* __restrict__ plocs, const float4* __restrict__ scores,
    const float* __restrict__ scoresF, const float4* __restrict__ boxes,
    const int* __restrict__ labels, const float4* __restrict__ priors,
    const unsigned long long* __restrict__ objbest,
    float* __restrict__ partF, float* __restrict__ partS,
    int* __restrict__ partN) {
  const int b    = blockIdx.y;
  const int base = blockIdx.x * 256;
  const int tid  = threadIdx.x;
  const int p    = base + tid;
  const int lane = tid & 63, wid = tid >> 6;

  __shared__ float4 sbox[NOBJ];
  __shared__ float  sarea[NOBJ];
  __shared__ int    slab[NOBJ];
  __shared__ int    sfp[NOBJ];   // forced prior index (-1 if invalid)
  __shared__ int    sfc[NOBJ];   // filtered object index (cumsum(valid)-1)
  __shared__ int    igp[256];    // compacted ignored prior indices
  __shared__ int    wcnt[4];     // per-wave ignored counts

  if (tid < NOBJ) {
    float4 bx = boxes[b * NOBJ + tid];
    sbox[tid]  = bx;
    sarea[tid] = (bx.z - bx.x) * (bx.w - bx.y);
    slab[tid]  = labels[b * NOBJ + tid];
    unsigned long long pk = objbest[b * NOBJ + tid];
    float iou  = __uint_as_float((unsigned)(pk >> 32));
    bool valid = iou > 0.f;
    unsigned long long m = __ballot(valid);       // lanes 32..63 inactive -> 0
    sfp[tid] = valid ? (int)(~(unsigned)(pk & 0xFFFFFFFFull)) : -1;
    sfc[tid] = (int)__popcll(m & ((1ull << tid) - 1ull));
  }

  // ---- phase 1: bulk focal over this chunk's 256x20 float4 slab
  const int nval = (P - base < 256) ? (P - base) : 256;
  const float4* srow = scores + ((size_t)b * P + base) * 20;
  float acc = 0.f;
  if (nval == 256) {                   // full chunk: 5120 float4, unguarded
    #pragma unroll
    for (int bt = 0; bt < 2; ++bt) {
      float4 s[10];
      const int i0 = tid + bt * 2560;
      #pragma unroll
      for (int j = 0; j < 10; ++j) s[j] = srow[i0 + j * 256];  // coalesced
      #pragma unroll
      for (int j = 0; j < 10; ++j)
        acc += negterm(s[j].x) + negterm(s[j].y)
             + negterm(s[j].z) + negterm(s[j].w);
    }
  } else {                             // tail chunk (1 per image)
    const int lim = nval * 20;
    for (int idx = tid; idx < lim; idx += 256) {
      float4 s = srow[idx];
      acc += negterm(s.x) + negterm(s.y) + negterm(s.z) + negterm(s.w);
    }
  }
  __syncthreads();                     // sbox/sfp staging complete

  // ---- phase 2: match + force + classloc + corrections (R15 prep body)
  float mySl1 = 0.f, myCorr = 0.f; int myPos = 0;
  bool isig = false;
  if (p < P) {
    float4 pc = priors[p];
    float hx = pc.z * 0.5f, hy = pc.w * 0.5f;
    float px0 = pc.x - hx, py0 = pc.y - hy;
    float px1 = pc.x + hx, py1 = pc.y + hy;
    float parea = (px1 - px0) * (py1 - py0);
    float bi = 0.f, bu = 1.f; int obj = 0;       // best inter/union/object
    #pragma unroll 8
    for (int o = 0; o < NOBJ; ++o) {
      float4 bx = sbox[o];
      float lx = fmaxf(bx.x, px0), ly = fmaxf(bx.y, py0);
      float rx = fminf(bx.z, px1), ry = fminf(bx.w, py1);
      float w = fmaxf(rx - lx, 0.f), h = fmaxf(ry - ly, 0.f);
      float inter = w * h;
      float uni = sarea[o] + parea - inter;      // reference operand order
      if (inter * bu > bi * uni) { bi = inter; bu = uni; obj = o; }
      // strict >: first max wins (ascending o)
    }
    float ov = bi / bu;                          // ONE IEEE div: ref bits
    #pragma unroll
    for (int j = 0; j < NOBJ; ++j) {             // ascending j: last writer wins
      if (sfp[j] == p) { ov = 1.0f; obj = sfc[j]; }
    }
    int lab;
    if (ov < 0.4f)      lab = 0;                 // fp32(0.5-0.1) == 0.4f
    else if (ov < 0.5f) lab = -1;
    else                lab = slab[obj];
    if (lab < 0) {
      isig = true;                               // handled cooperatively below
    } else if (lab > 0) {
      myPos = 1;
      float4 bx = sbox[obj];                     // quirky filtered index, like ref
      float cx = (bx.x + bx.z) * 0.5f;
      float cy = (bx.y + bx.w) * 0.5f;
      float cw = bx.z - bx.x;
      float ch = bx.w - bx.y;
      float gx = (cx - pc.x) / (pc.z / 10.f);    // keep the /10. division
      float gy = (cy - pc.y) / (pc.w / 10.f);
      float gw = logf(cw / pc.z) * 5.f;
      float gh = logf(ch / pc.w) * 5.f;
      float4 pl = plocs[(size_t)b * P + p];
      float d, a;
      d = pl.x - gx; a = fabsf(d); mySl1 += (a < 1.f) ? 0.5f * d * d : a - 0.5f;
      d = pl.y - gy; a = fabsf(d); mySl1 += (a < 1.f) ? 0.5f * d * d : a - 0.5f;
      d = pl.z - gw; a = fabsf(d); mySl1 += (a < 1.f) ? 0.5f * d * d : a - 0.5f;
      d = pl.w - gh; a = fabsf(d); mySl1 += (a < 1.f) ? 0.5f * d * d : a - 0.5f;
      // swap the positive class's neg term for the pos term
      float x  = scoresF[((size_t)b * P + p) * NCLS + (lab - 1)];
      float e  = __expf(-x);
      float u  = 1.f + e;
      float r  = __builtin_amdgcn_rcpf(u);
      float lu = __logf(u);
      float omp = e * r;                         // 1-p
      myCorr += 0.25f * omp * omp * lu - 0.75f * (x + lu) * (r * r);
    }
  }

  // ---- deterministic compaction of ignored priors (ballot prefix, no atomics)
  unsigned long long igm = __ballot(isig);
  int wpre = (int)__popcll(igm & ((1ull << lane) - 1ull));
  if (lane == 0) wcnt[wid] = (int)__popcll(igm);
  __syncthreads();
  int wbase = 0;
  #pragma unroll
  for (int ww = 0; ww < 4; ++ww) if (ww < wid) wbase += wcnt[ww];
  const int n_ig = wcnt[0] + wcnt[1] + wcnt[2] + wcnt[3];
  if (isig) igp[wbase + wpre] = p;
  __syncthreads();

  // ---- cooperative recompute of ignored rows: 4 threads/row, 5 float4 each
  const float4* scores4 = (const float4*)scoresF;
  for (int i0 = 0; i0 < n_ig; i0 += 64) {
    int r = i0 + (tid >> 2);
    int q = tid & 3;
    float rs = 0.f;
    if (r < n_ig) {
      const float4* row = scores4 + ((size_t)b * P + igp[r]) * 20 + q * 5;
      #pragma unroll
      for (int j = 0; j < 5; ++j) {
        float4 s = row[j];                 // 80B contiguous per lane
        rs += negterm(s.x) + negterm(s.y) + negterm(s.z) + negterm(s.w);
      }
    }
    rs += __shfl_xor(rs, 1, 64);
    rs += __shfl_xor(rs, 2, 64);
    if (r < n_ig && q == 0) myCorr -= 0.75f * rs;
  }

  // ---- block reduce (focal + corrections combined)
  float myF = 0.75f * acc + myCorr;
  for (int off = 32; off > 0; off >>= 1) {
    myF   += __shfl_down(myF,   off, 64);
    mySl1 += __shfl_down(mySl1, off, 64);
    myPos += __shfl_down(myPos, off, 64);
  }
  __shared__ float sv[4], sc2[4];
  __shared__ int   sc[4];
  if (lane == 0) { sc2[wid] = myF; sv[wid] = mySl1; sc[wid] = myPos; }
  __syncthreads();
  if (tid == 0) {
    const int bid = b * CHUNKS + blockIdx.x;
    partF[bid] = sc2[0] + sc2[1] + sc2[2] + sc2[3];
    partS[bid] = sv[0] + sv[1] + sv[2] + sv[3];
    partN[bid] = sc[0] + sc[1] + sc[2] + sc[3];
  }
}

// ---------------------------------------------------------------- K3: final reduce
__global__ __launch_bounds__(256) void k_final(
    const float* __restrict__ partF, const float* __restrict__ partS,
    const int* __restrict__ partN, float* __restrict__ out) {
  const int tid = threadIdx.x;
  float sF = 0.f, sS = 0.f; int sN = 0;
  for (int i = tid; i < NBLK; i += 256) {
    sF += partF[i];
    sS += partS[i];
    sN += partN[i];
  }
  for (int off = 32; off > 0; off >>= 1) {
    sF += __shfl_down(sF, off, 64);
    sS += __shfl_down(sS, off, 64);
    sN += __shfl_down(sN, off, 64);
  }
  __shared__ float vF[4], vS[4];
  __shared__ int   vN[4];
  int lane = tid & 63, wid = tid >> 6;
  if (lane == 0) { vF[wid] = sF; vS[wid] = sS; vN[wid] = sN; }
  __syncthreads();
  if (tid == 0) {
    float f = vF[0] + vF[1] + vF[2] + vF[3];
    float s = vS[0] + vS[1] + vS[2] + vS[3];
    int   n = vN[0] + vN[1] + vN[2] + vN[3];
    float np = (float)(n >= 1 ? n : 1);
    out[0] = f / np + s / (np * 4.f);
  }
}

// ---------------------------------------------------------------- launch
extern "C" void kernel_launch(void* const* d_in, const int* in_sizes, int n_in,
                              void* d_out, int out_size, void* d_ws, size_t ws_size,
                              hipStream_t stream) {
  const float* plocs   = (const float*)d_in[0];   // [B,P,4]
  const float* pscores = (const float*)d_in[1];   // [B,P,80]
  const float* boxes   = (const float*)d_in[2];   // [B,32,4]
  const int*   labels  = (const int*)d_in[3];     // [B,32]
  const float* priors  = (const float*)d_in[4];   // [P,4]
  float* out = (float*)d_out;

  char* w = (char*)d_ws;
  unsigned long long* objbest = (unsigned long long*)w;  // 512 u64  @0
  float* partF = (float*)(w + 4096);                     // NBLK floats
  float* partS = (float*)(w + 16384);                    // NBLK floats
  int*   partN = (int*)(w + 28672);                      // NBLK ints

  k_objbest<<<OBJB, 256, 0, stream>>>(
      (const float4*)boxes, (const float4*)priors, objbest);
  dim3 g(CHUNKS, B);
  k_fused<<<g, 256, 0, stream>>>(
      (const float4*)plocs, (const float4*)pscores, pscores,
      (const float4*)boxes, labels, (const float4*)priors, objbest,
      partF, partS, partN);
  k_final<<<1, 256, 0, stream>>>(partF, partS, partN, out);
}

// Round 21
// 51.507 us; speedup vs baseline: 1.5370x; 1.0841x over previous
//
#include <hip/hip_runtime.h>
#include <cstdint>

static constexpr int B    = 16;
static constexpr int P    = 22536;
static constexpr int NOBJ = 32;
static constexpr int NCLS = 80;
static constexpr int CHUNKS = (P + 255) / 256;   // 89
static constexpr int NBLK   = CHUNKS * B;        // 1424 bulk blocks
static constexpr int OBJB   = B * NOBJ;          // 512 objbest blocks

// neg-path focal term (before the 0.75 weight): p^2*(x+log u), u=1+e^-x, p=1/u
__device__ __forceinline__ float negterm(float x) {
  float e  = __expf(-x);
  float u  = 1.f + e;
  float r  = __builtin_amdgcn_rcpf(u);
  float lu = __logf(u);
  return (x + lu) * (r * r);
}

// ---------------------------------------------------------------- Node 1: pure bulk focal + objbest (division-free scan)
// R15 configuration (best measured: 51.6 us total).
__global__ __launch_bounds__(256, 4) void k_bulk(
    const float4* __restrict__ scores, const float4* __restrict__ boxes,
    const float4* __restrict__ priors,
    float* __restrict__ partB, unsigned long long* __restrict__ objbest) {
  const int bid = blockIdx.x;
  const int tid = threadIdx.x;
  if (bid < NBLK) {
    const int b    = bid / CHUNKS;
    const int base = (bid - b * CHUNKS) * 256;
    const int nval = (P - base < 256) ? (P - base) : 256;
    const float4* srow = scores + ((size_t)b * P + base) * 20;
    float acc = 0.f;
    if (nval == 256) {                   // full chunk: 5120 float4, unguarded
      #pragma unroll
      for (int bt = 0; bt < 2; ++bt) {
        float4 s[10];
        const int i0 = tid + bt * 2560;
        #pragma unroll
        for (int j = 0; j < 10; ++j) s[j] = srow[i0 + j * 256];  // coalesced
        #pragma unroll
        for (int j = 0; j < 10; ++j)
          acc += negterm(s[j].x) + negterm(s[j].y)
               + negterm(s[j].z) + negterm(s[j].w);
      }
    } else {                             // tail chunk (1 per image)
      const int lim = nval * 20;
      for (int idx = tid; idx < lim; idx += 256) {
        float4 s = srow[idx];
        acc += negterm(s.x) + negterm(s.y) + negterm(s.z) + negterm(s.w);
      }
    }
    acc *= 0.75f;
    for (int off = 32; off > 0; off >>= 1) acc += __shfl_down(acc, off, 64);
    __shared__ float sv[4];
    int lane = tid & 63, wid = tid >> 6;
    if (lane == 0) sv[wid] = acc;
    __syncthreads();
    if (tid == 0) partB[bid] = sv[0] + sv[1] + sv[2] + sv[3];
  } else {
    // -------- objbest role: division-free argmax scan
    const int bid2 = bid - NBLK;
    const int b = bid2 >> 5;
    const int o = bid2 & (NOBJ - 1);
    float4 bx = boxes[b * NOBJ + o];
    float barea = (bx.z - bx.x) * (bx.w - bx.y);   // reference op order
    float bi = 0.f, bu = 1.f; int bp = P;          // best inter/union/prior
    #pragma unroll 4
    for (int p = tid; p < P; p += 256) {
      float4 pc = priors[p];
      float hx = pc.z * 0.5f, hy = pc.w * 0.5f;    // c/2. == c*0.5f exactly
      float px0 = pc.x - hx, py0 = pc.y - hy;
      float px1 = pc.x + hx, py1 = pc.y + hy;
      float parea = (px1 - px0) * (py1 - py0);
      float lx = fmaxf(bx.x, px0), ly = fmaxf(bx.y, py0);
      float rx = fminf(bx.z, px1), ry = fminf(bx.w, py1);
      float w = fmaxf(rx - lx, 0.f), h = fmaxf(ry - ly, 0.f);
      float inter = w * h;
      float uni = barea + parea - inter;           // reference operand order
      // iou_p > iou_best  <=>  inter*bu > bi*uni  (all positive)
      if (inter * bu > bi * uni) { bi = inter; bu = uni; bp = p; }
    }
    for (int off = 32; off > 0; off >>= 1) {
      float oi = __shfl_down(bi, off, 64);
      float ou = __shfl_down(bu, off, 64);
      int   op = __shfl_down(bp, off, 64);
      float l = oi * bu, r2 = bi * ou;
      if (l > r2 || (l == r2 && op < bp)) { bi = oi; bu = ou; bp = op; }
    }
    __shared__ float sbi[4], sbu[4];
    __shared__ int   sbp[4];
    int lane = tid & 63, wid = tid >> 6;
    if (lane == 0) { sbi[wid] = bi; sbu[wid] = bu; sbp[wid] = bp; }
    __syncthreads();
    if (tid == 0) {
      for (int w2 = 1; w2 < 4; ++w2) {
        float l = sbi[w2] * bu, r2 = bi * sbu[w2];
        if (l > r2 || (l == r2 && sbp[w2] < bp)) {
          bi = sbi[w2]; bu = sbu[w2]; bp = sbp[w2];
        }
      }
      float iou = bi / bu;                 // ONE IEEE div: reference bits
      objbest[bid2] =
          ((unsigned long long)__float_as_uint(iou) << 32) |
          (unsigned long long)(unsigned)(~(unsigned)bp);
    }
  }
}

// ---------------------------------------------------------------- Node 2: match + force + classloc + focal corrections
// R15 configuration. Div-free per-prior argmax (cross-mult), ONE IEEE div for
// the winner's ov (reference bits for 0.4/0.5 thresholds). Forced-list ballot
// prefix = cumsum(valid)-1 quirk; ascending-j overwrite = last-writer-wins.
// Ignored rows compacted (ballot prefix) + recomputed cooperatively.
__global__ __launch_bounds__(256) void k_prep(
    const float4* __restrict__ plocs, const float* __restrict__ scoresF,
    const float4* __restrict__ boxes, const int* __restrict__ labels,
    const float4* __restrict__ priors,
    const unsigned long long* __restrict__ objbest,
    float* __restrict__ partS, int* __restrict__ partN,
    float* __restrict__ partC) {
  const int b    = blockIdx.y;
  const int base = blockIdx.x * 256;
  const int tid  = threadIdx.x;
  const int p    = base + tid;
  const int lane = tid & 63, wid = tid >> 6;

  __shared__ float4 sbox[NOBJ];
  __shared__ float  sarea[NOBJ];
  __shared__ int    slab[NOBJ];
  __shared__ int    sfp[NOBJ];   // forced prior index (-1 if invalid)
  __shared__ int    sfc[NOBJ];   // filtered object index (cumsum(valid)-1)
  __shared__ int    igp[256];    // compacted ignored prior indices
  __shared__ int    wcnt[4];     // per-wave ignored counts

  if (tid < NOBJ) {
    float4 bx = boxes[b * NOBJ + tid];
    sbox[tid]  = bx;
    sarea[tid] = (bx.z - bx.x) * (bx.w - bx.y);
    slab[tid]  = labels[b * NOBJ + tid];
    unsigned long long pk = objbest[b * NOBJ + tid];
    float iou  = __uint_as_float((unsigned)(pk >> 32));
    bool valid = iou > 0.f;
    unsigned long long m = __ballot(valid);       // lanes 32..63 inactive -> 0
    sfp[tid] = valid ? (int)(~(unsigned)(pk & 0xFFFFFFFFull)) : -1;
    sfc[tid] = (int)__popcll(m & ((1ull << tid) - 1ull));
  }
  __syncthreads();

  float mySl1 = 0.f, myCorr = 0.f; int myPos = 0;
  bool isig = false;
  if (p < P) {
    float4 pc = priors[p];
    float hx = pc.z * 0.5f, hy = pc.w * 0.5f;
    float px0 = pc.x - hx, py0 = pc.y - hy;
    float px1 = pc.x + hx, py1 = pc.y + hy;
    float parea = (px1 - px0) * (py1 - py0);
    float bi = 0.f, bu = 1.f; int obj = 0;       // best inter/union/object
    #pragma unroll 8
    for (int o = 0; o < NOBJ; ++o) {
      float4 bx = sbox[o];
      float lx = fmaxf(bx.x, px0), ly = fmaxf(bx.y, py0);
      float rx = fminf(bx.z, px1), ry = fminf(bx.w, py1);
      float w = fmaxf(rx - lx, 0.f), h = fmaxf(ry - ly, 0.f);
      float inter = w * h;
      float uni = sarea[o] + parea - inter;      // reference operand order
      if (inter * bu > bi * uni) { bi = inter; bu = uni; obj = o; }
      // strict >: first max wins (ascending o)
    }
    float ov = bi / bu;                          // ONE IEEE div: ref bits
    #pragma unroll
    for (int j = 0; j < NOBJ; ++j) {             // ascending j: last writer wins
      if (sfp[j] == p) { ov = 1.0f; obj = sfc[j]; }
    }
    int lab;
    if (ov < 0.4f)      lab = 0;                 // fp32(0.5-0.1) == 0.4f
    else if (ov < 0.5f) lab = -1;
    else                lab = slab[obj];
    if (lab < 0) {
      isig = true;                               // handled cooperatively below
    } else if (lab > 0) {
      myPos = 1;
      float4 bx = sbox[obj];                     // quirky filtered index, like ref
      float cx = (bx.x + bx.z) * 0.5f;
      float cy = (bx.y + bx.w) * 0.5f;
      float cw = bx.z - bx.x;
      float ch = bx.w - bx.y;
      float gx = (cx - pc.x) / (pc.z / 10.f);    // keep the /10. division
      float gy = (cy - pc.y) / (pc.w / 10.f);
      float gw = logf(cw / pc.z) * 5.f;
      float gh = logf(ch / pc.w) * 5.f;
      float4 pl = plocs[(size_t)b * P + p];
      float d, a;
      d = pl.x - gx; a = fabsf(d); mySl1 += (a < 1.f) ? 0.5f * d * d : a - 0.5f;
      d = pl.y - gy; a = fabsf(d); mySl1 += (a < 1.f) ? 0.5f * d * d : a - 0.5f;
      d = pl.z - gw; a = fabsf(d); mySl1 += (a < 1.f) ? 0.5f * d * d : a - 0.5f;
      d = pl.w - gh; a = fabsf(d); mySl1 += (a < 1.f) ? 0.5f * d * d : a - 0.5f;
      // swap the positive class's neg term for the pos term
      float x  = scoresF[((size_t)b * P + p) * NCLS + (lab - 1)];
      float e  = __expf(-x);
      float u  = 1.f + e;
      float r  = __builtin_amdgcn_rcpf(u);
      float lu = __logf(u);
      float omp = e * r;                         // 1-p
      myCorr += 0.25f * omp * omp * lu - 0.75f * (x + lu) * (r * r);
    }
  }

  // ---- deterministic compaction of ignored priors (ballot prefix, no atomics)
  unsigned long long igm = __ballot(isig);
  int wpre = (int)__popcll(igm & ((1ull << lane) - 1ull));
  if (lane == 0) wcnt[wid] = (int)__popcll(igm);
  __syncthreads();
  int wbase = 0;
  #pragma unroll
  for (int ww = 0; ww < 4; ++ww) if (ww < wid) wbase += wcnt[ww];
  const int n_ig = wcnt[0] + wcnt[1] + wcnt[2] + wcnt[3];
  if (isig) igp[wbase + wpre] = p;
  __syncthreads();

  // ---- cooperative recompute of ignored rows: 4 threads/row, 5 float4 each
  const float4* scores4 = (const float4*)scoresF;
  for (int i0 = 0; i0 < n_ig; i0 += 64) {
    int r = i0 + (tid >> 2);
    int q = tid & 3;
    float rs = 0.f;
    if (r < n_ig) {
      const float4* row = scores4 + ((size_t)b * P + igp[r]) * 20 + q * 5;
      #pragma unroll
      for (int j = 0; j < 5; ++j) {
        float4 s = row[j];                 // 80B contiguous per lane
        rs += negterm(s.x) + negterm(s.y) + negterm(s.z) + negterm(s.w);
      }
    }
    rs += __shfl_xor(rs, 1, 64);
    rs += __shfl_xor(rs, 2, 64);
    if (r < n_ig && q == 0) myCorr -= 0.75f * rs;
  }

  for (int off = 32; off > 0; off >>= 1) {
    mySl1  += __shfl_down(mySl1,  off, 64);
    myCorr += __shfl_down(myCorr, off, 64);
    myPos  += __shfl_down(myPos,  off, 64);
  }
  __shared__ float sv[4], sc2[4];
  __shared__ int   sc[4];
  if (lane == 0) { sv[wid] = mySl1; sc2[wid] = myCorr; sc[wid] = myPos; }
  __syncthreads();
  if (tid == 0) {
    const int bid = b * CHUNKS + blockIdx.x;
    partS[bid] = sv[0] + sv[1] + sv[2] + sv[3];
    partC[bid] = sc2[0] + sc2[1] + sc2[2] + sc2[3];
    partN[bid] = sc[0] + sc[1] + sc[2] + sc[3];
  }
}

// ---------------------------------------------------------------- Node 3: final reduce
__global__ __launch_bounds__(256) void k_final(
    const float* __restrict__ partB, const float* __restrict__ partC,
    const float* __restrict__ partS, const int* __restrict__ partN,
    float* __restrict__ out) {
  const int tid = threadIdx.x;
  float sF = 0.f, sS = 0.f; int sN = 0;
  for (int i = tid; i < NBLK; i += 256) {
    sF += partB[i] + partC[i];
    sS += partS[i];
    sN += partN[i];
  }
  for (int off = 32; off > 0; off >>= 1) {
    sF += __shfl_down(sF, off, 64);
    sS += __shfl_down(sS, off, 64);
    sN += __shfl_down(sN, off, 64);
  }
  __shared__ float vF[4], vS[4];
  __shared__ int   vN[4];
  int lane = tid & 63, wid = tid >> 6;
  if (lane == 0) { vF[wid] = sF; vS[wid] = sS; vN[wid] = sN; }
  __syncthreads();
  if (tid == 0) {
    float f = vF[0] + vF[1] + vF[2] + vF[3];
    float s = vS[0] + vS[1] + vS[2] + vS[3];
    int   n = vN[0] + vN[1] + vN[2] + vN[3];
    float np = (float)(n >= 1 ? n : 1);
    out[0] = f / np + s / (np * 4.f);
  }
}

// ---------------------------------------------------------------- launch
extern "C" void kernel_launch(void* const* d_in, const int* in_sizes, int n_in,
                              void* d_out, int out_size, void* d_ws, size_t ws_size,
                              hipStream_t stream) {
  const float* plocs   = (const float*)d_in[0];   // [B,P,4]
  const float* pscores = (const float*)d_in[1];   // [B,P,80]
  const float* boxes   = (const float*)d_in[2];   // [B,32,4]
  const int*   labels  = (const int*)d_in[3];     // [B,32]
  const float* priors  = (const float*)d_in[4];   // [P,4]
  float* out = (float*)d_out;

  char* w = (char*)d_ws;
  unsigned long long* objbest = (unsigned long long*)w;  // 512 u64  @0
  float* partB = (float*)(w + 4096);                     // NBLK floats
  float* partS = (float*)(w + 16384);                    // NBLK floats
  int*   partN = (int*)(w + 28672);                      // NBLK ints
  float* partC = (float*)(w + 40960);                    // NBLK floats

  k_bulk<<<NBLK + OBJB, 256, 0, stream>>>(
      (const float4*)pscores, (const float4*)boxes, (const float4*)priors,
      partB, objbest);
  dim3 g(CHUNKS, B);
  k_prep<<<g, 256, 0, stream>>>(
      (const float4*)plocs, pscores, (const float4*)boxes, labels,
      (const float4*)priors, objbest, partS, partN, partC);
  k_final<<<1, 256, 0, stream>>>(partB, partC, partS, partN, out);
}